// Round 11
// baseline (92.603 us; speedup 1.0000x reference)
//
#include <hip/hip_runtime.h>

#define NEXP 8
#define NRANK 256
typedef unsigned long long u64;
typedef unsigned int u32;

// ---------------- kernel 1: fused probs (blocks [0,npb)) + zero-fill ----------
// (verbatim from the 71.2 µs round-6 kernel)
__global__ __launch_bounds__(512) void probs_fill_kernel(
    const float* __restrict__ x,      // [GT, 1024]
    const float* __restrict__ w,      // [8, 1024]
    const float* __restrict__ bias,   // [8]
    float* __restrict__ probsT,       // [E][GT]
    double* __restrict__ zpart,       // [npb]
    int* __restrict__ flags,          // [8] -> zeroed here for kernel 2
    float* __restrict__ out,
    long long nout4,
    long long GT, int npb, int nfb)
{
    if (blockIdx.x == 0 && threadIdx.x < 8) flags[threadIdx.x] = 0;

    if ((int)blockIdx.x >= npb) {
        const int fb = (int)blockIdx.x - npb;
        const long long stride = (long long)nfb * 512;
        const float4 z = make_float4(0.f, 0.f, 0.f, 0.f);
        for (long long k = (long long)fb * 512 + threadIdx.x; k < nout4; k += stride) {
            reinterpret_cast<float4*>(out)[k] = z;
        }
        return;
    }

    __shared__ float wl[NEXP * 1024];
    __shared__ double zred[8];
    for (int i = threadIdx.x; i < NEXP * 1024 / 4; i += 512) {
        reinterpret_cast<float4*>(wl)[i] = reinterpret_cast<const float4*>(w)[i];
    }
    __syncthreads();

    const int wave = threadIdx.x >> 6;
    const int lane = threadIdx.x & 63;
    const long long t = (long long)blockIdx.x * 8 + wave;
    const float* xr = x + t * 1024;

    float acc[NEXP];
#pragma unroll
    for (int e = 0; e < NEXP; ++e) acc[e] = 0.f;

#pragma unroll
    for (int c = 0; c < 4; ++c) {
        const int d = c * 256 + lane * 4;
        const float4 xv = *reinterpret_cast<const float4*>(xr + d);
#pragma unroll
        for (int e = 0; e < NEXP; ++e) {
            const float4 wv = *reinterpret_cast<const float4*>(wl + e * 1024 + d);
            acc[e] = fmaf(xv.x, wv.x, acc[e]);
            acc[e] = fmaf(xv.y, wv.y, acc[e]);
            acc[e] = fmaf(xv.z, wv.z, acc[e]);
            acc[e] = fmaf(xv.w, wv.w, acc[e]);
        }
    }
#pragma unroll
    for (int e = 0; e < NEXP; ++e) {
#pragma unroll
        for (int off = 32; off; off >>= 1) acc[e] += __shfl_xor(acc[e], off, 64);
    }

    if (lane == 0) {
        double l[NEXP];
        double mx = -1e300;
#pragma unroll
        for (int e = 0; e < NEXP; ++e) {
            l[e] = (double)acc[e] + (double)bias[e];
            mx = fmax(mx, l[e]);
        }
        double ex[NEXP];
        double s = 0.0;
#pragma unroll
        for (int e = 0; e < NEXP; ++e) { ex[e] = exp(l[e] - mx); s += ex[e]; }
        const double inv = 1.0 / s;
#pragma unroll
        for (int e = 0; e < NEXP; ++e) probsT[(long long)e * GT + t] = (float)(ex[e] * inv);
        const double lse = mx + log(s);
        zred[wave] = lse * lse;
    }
    __syncthreads();
    if (threadIdx.x == 0) {
        double s = 0.0;
#pragma unroll
        for (int i = 0; i < 8; ++i) s += zred[i];
        zpart[blockIdx.x] = s;
    }
}

// ------- kernel 2: rank (blocks 0..255, 1024 thr) + assign (1 wave/group) ----
union __align__(16) Smem2 {
    struct { u64 keys[2048]; int part[1024]; } b;   // rank path (20 KB)
    struct { int avail[2048]; } c;                  // assign path (8 KB)
};

__global__ __launch_bounds__(1024) void rank_assign_kernel(
    const float* __restrict__ probsT,  // [E][GT]
    u64* __restrict__ skey,            // [E*G][T]
    int* __restrict__ flags,           // zeroed by kernel 1
    const double* __restrict__ zpart,
    int nzpart,
    float* __restrict__ out,
    long long nout4, int out_size,
    int T, int G, int cap, long long GT)
{
    __shared__ Smem2 sm;
    const int b = blockIdx.x;
    const int tid = threadIdx.x;

    if (b < NRANK) {
        // ---- ranksort slice: pair = e*G+g, 1/8 of its 2048 tokens (R6 code) ----
        const int pair = b >> 3;
        const int sub  = b & 7;
        const int e = pair / G;
        const int g = pair - e * G;
        const float* p = probsT + (long long)e * GT + (long long)g * T;
        for (int j = tid; j < 2048; j += 1024)
            sm.b.keys[j] = ((u64)__float_as_uint(p[j]) << 32) | (u32)(~(u32)j);
        __syncthreads();
        const int slot = tid & 255;
        const int q = tid >> 8;            // compare-range quarter 0..3
        const u64 kt = sm.b.keys[sub * 256 + slot];
        const ulonglong2* k2p = reinterpret_cast<const ulonglong2*>(sm.b.keys) + q * 256;
        int r = 0;
#pragma unroll 8
        for (int j = 0; j < 256; ++j) {
            const ulonglong2 v = k2p[j];
            r += (v.x > kt); r += (v.y > kt);
        }
        sm.b.part[tid] = r;
        __syncthreads();
        if (tid < 256) {
            const int rank = sm.b.part[tid] + sm.b.part[tid + 256] + sm.b.part[tid + 512] + sm.b.part[tid + 768];
            skey[(long long)pair * T + rank] = sm.b.keys[sub * 256 + tid];
        }
        __syncthreads();   // skey stores drained before flag release
        if (tid == 0) { __threadfence(); atomicAdd(&flags[g], 1); }
        return;
    }

    // ---- assign for group g: ONE WAVE, zero barriers ----
    const int g = b - NRANK;
    if (tid >= 64) return;                 // lanes 64.. exit; no barriers below
    const int lane = tid;

    // all 64 lanes spin on the same flag (uniform exit)
    while (__hip_atomic_load(&flags[g], __ATOMIC_RELAXED, __HIP_MEMORY_SCOPE_AGENT) < NRANK / 4)
        __builtin_amdgcn_s_sleep(2);
    __threadfence();                       // acquire: skey visible

    for (int j = lane; j < 2048; j += 64) sm.c.avail[j] = 1;

    const u64 lmask = (lane == 0) ? 0ull : ((~0ull) >> (64 - lane));
    const long long gbase = (long long)g * T;
    float* dispatch = out;
    float* combine  = out + GT * (long long)NEXP * cap;

    u64 kc[32];
#pragma unroll 1
    for (int e = 0; e < NEXP; ++e) {
        const long long kb = (long long)(e * G + g) * T;
#pragma unroll
        for (int c = 0; c < 32; ++c) kc[c] = skey[kb + c * 64 + lane];  // rank 64c+lane

        u32 selmask = 0;
        int scount = 0;                    // running count of available (uniform)
#pragma unroll
        for (int cc = 0; cc < 4; ++cc) {
            int av[8];
#pragma unroll
            for (int j = 0; j < 8; ++j)
                av[j] = sm.c.avail[(~(u32)kc[cc * 8 + j]) & 2047u];
#pragma unroll
            for (int j = 0; j < 8; ++j) {
                const int c = cc * 8 + j;
                const u64 m = __ballot(av[j] != 0);
                const int pre = scount + __popcll(m & lmask);
                if (av[j] && pre < cap) {
                    const u32 idx = (~(u32)kc[c]) & 2047u;
                    const long long o_ = ((gbase + idx) * NEXP + e) * (long long)cap + pre;
                    dispatch[o_] = 1.0f;
                    combine[o_]  = __uint_as_float((u32)(kc[c] >> 32));
                    selmask |= (1u << c);
                }
                scount += __popcll(m);
            }
        }
        const int S = scount;
        if (S < cap) {
            // zero-gate fill: smallest-index unavailable tokens (pre-update avail)
            const int nfill = cap - S;
            int zc = 0;
#pragma unroll
            for (int c = 0; c < 32; ++c) {
                const int un = (sm.c.avail[c * 64 + lane] == 0);
                const u64 mn = __ballot(un);
                const int qz = zc + __popcll(mn & lmask);
                if (un && qz < nfill) {
                    const long long o_ = ((gbase + c * 64 + lane) * NEXP + e) * (long long)cap + (S + qz);
                    dispatch[o_] = 1.0f;
                }
                zc += __popcll(mn);
            }
        }
        // deferred avail updates (same-expert list is a permutation -> safe)
#pragma unroll
        for (int c = 0; c < 32; ++c)
            if (selmask & (1u << c)) sm.c.avail[(~(u32)kc[c]) & 2047u] = 0;
    }

    // z_loss + tail scalars (group-0 wave)
    if (g == 0) {
        double s = 0.0;
        for (int i = lane; i < nzpart; i += 64) s += zpart[i];
#pragma unroll
        for (int o = 32; o; o >>= 1) s += __shfl_xor(s, o, 64);
        if (lane == 0) {
            float* sc = out + 2 * GT * (long long)NEXP * cap;
            for (long long j = nout4 * 4; j < (long long)out_size - 3; ++j) out[j] = 0.f;
            sc[0] = 0.0f;
            sc[1] = (float)(s / (double)GT);
            sc[2] = 0.0f;
        }
    }
}

extern "C" void kernel_launch(void* const* d_in, const int* in_sizes, int n_in,
                              void* d_out, int out_size, void* d_ws, size_t ws_size,
                              hipStream_t stream) {
    (void)n_in; (void)ws_size;
    const float* x    = (const float*)d_in[0];
    const float* w    = (const float*)d_in[1];
    const float* bias = (const float*)d_in[2];

    const int E = in_sizes[2];                        // 8
    const int D = in_sizes[1] / E;                    // 1024
    const long long GT = (long long)in_sizes[0] / D;  // 8192
    const int T = 2048;
    const int G = (int)(GT / T);                      // 4
    const int cap = (int)(((long long)out_size - 3) / (2 * GT * E));
    const int npb = (int)(GT / 8);                    // 1024 probs blocks
    const int nfb = 2048;                             // fill blocks

    int*    flags  = (int*)d_ws;                                   // [0,32)
    double* zpart  = (double*)((char*)d_ws + 4096);                // npb*8 B
    float*  probsT = (float*)((char*)d_ws + 16384);                // E*GT*4
    u64*    skey   = (u64*)((char*)d_ws + 16384 + (size_t)E * GT * sizeof(float));

    const long long nout4 = ((long long)out_size - 3) >> 2;

    probs_fill_kernel<<<npb + nfb, 512, 0, stream>>>(
        x, w, bias, probsT, zpart, flags, (float*)d_out, nout4, GT, npb, nfb);

    rank_assign_kernel<<<NRANK + G, 1024, 0, stream>>>(
        probsT, skey, flags, zpart, npb, (float*)d_out, nout4, out_size, T, G, cap, GT);
}

// Round 13
// 71.356 us; speedup vs baseline: 1.2978x; 1.2978x over previous
//
#include <hip/hip_runtime.h>

#define NEXP 8
#define NRANK 256
typedef unsigned long long u64;
typedef unsigned int u32;
typedef float f32x4 __attribute__((ext_vector_type(4)));   // clang vector (nt-store OK)

#define LOAD_AGT(p)     __hip_atomic_load((p), __ATOMIC_RELAXED, __HIP_MEMORY_SCOPE_AGENT)
#define STORE_AGT(p,v)  __hip_atomic_store((p), (v), __ATOMIC_RELAXED, __HIP_MEMORY_SCOPE_AGENT)

// ---------------- kernel 1: fused probs (blocks [0,npb)) + zero-fill ----------
// R6 structure; fill uses nontemporal stores (streaming zeros, bypass L2).
__global__ __launch_bounds__(512) void probs_fill_kernel(
    const float* __restrict__ x,      // [GT, 1024]
    const float* __restrict__ w,      // [8, 1024]
    const float* __restrict__ bias,   // [8]
    float* __restrict__ probsT,       // [E][GT]
    double* __restrict__ zpart,       // [npb]
    int* __restrict__ flags,          // [4*16] -> zeroed here for kernel 2
    float* __restrict__ out,
    long long nout4,
    long long GT, int npb, int nfb)
{
    if (blockIdx.x == 0 && threadIdx.x < 64) flags[threadIdx.x] = 0;

    if ((int)blockIdx.x >= npb) {
        const int fb = (int)blockIdx.x - npb;
        const long long stride = (long long)nfb * 512;
        const f32x4 z = {0.f, 0.f, 0.f, 0.f};
        f32x4* o4 = reinterpret_cast<f32x4*>(out);
        for (long long k = (long long)fb * 512 + threadIdx.x; k < nout4; k += stride) {
            __builtin_nontemporal_store(z, o4 + k);
        }
        return;
    }

    __shared__ float wl[NEXP * 1024];
    __shared__ double zred[8];
    for (int i = threadIdx.x; i < NEXP * 1024 / 4; i += 512) {
        reinterpret_cast<float4*>(wl)[i] = reinterpret_cast<const float4*>(w)[i];
    }
    __syncthreads();

    const int wave = threadIdx.x >> 6;
    const int lane = threadIdx.x & 63;
    const long long t = (long long)blockIdx.x * 8 + wave;
    const float* xr = x + t * 1024;

    float acc[NEXP];
#pragma unroll
    for (int e = 0; e < NEXP; ++e) acc[e] = 0.f;

#pragma unroll
    for (int c = 0; c < 4; ++c) {
        const int d = c * 256 + lane * 4;
        const float4 xv = *reinterpret_cast<const float4*>(xr + d);
#pragma unroll
        for (int e = 0; e < NEXP; ++e) {
            const float4 wv = *reinterpret_cast<const float4*>(wl + e * 1024 + d);
            acc[e] = fmaf(xv.x, wv.x, acc[e]);
            acc[e] = fmaf(xv.y, wv.y, acc[e]);
            acc[e] = fmaf(xv.z, wv.z, acc[e]);
            acc[e] = fmaf(xv.w, wv.w, acc[e]);
        }
    }
#pragma unroll
    for (int e = 0; e < NEXP; ++e) {
#pragma unroll
        for (int off = 32; off; off >>= 1) acc[e] += __shfl_xor(acc[e], off, 64);
    }

    if (lane == 0) {
        double l[NEXP];
        double mx = -1e300;
#pragma unroll
        for (int e = 0; e < NEXP; ++e) {
            l[e] = (double)acc[e] + (double)bias[e];
            mx = fmax(mx, l[e]);
        }
        double ex[NEXP];
        double s = 0.0;
#pragma unroll
        for (int e = 0; e < NEXP; ++e) { ex[e] = exp(l[e] - mx); s += ex[e]; }
        const double inv = 1.0 / s;
#pragma unroll
        for (int e = 0; e < NEXP; ++e) probsT[(long long)e * GT + t] = (float)(ex[e] * inv);
        const double lse = mx + log(s);
        zred[wave] = lse * lse;
    }
    __syncthreads();
    if (threadIdx.x == 0) {
        double s = 0.0;
#pragma unroll
        for (int i = 0; i < 8; ++i) s += zred[i];
        zpart[blockIdx.x] = s;
    }
}

// ------- kernel 2: rank (blocks 0..255) + assign (blocks 256..259) -----------
// fence-free: skey goes through an LLC-coherent channel (agent atomics),
// flags padded 64B apart; no __threadfence (no buffer_wbl2 storms).
union __align__(16) Smem2 {
    struct { u64 keys[2048]; int part[1024]; } b;            // rank path (20 KB)
    struct { int avail[2048]; int cnt[32]; int cnt2[32]; } c; // assign path
};

__global__ __launch_bounds__(1024) void rank_assign_kernel(
    const float* __restrict__ probsT,  // [E][GT]
    u64* __restrict__ skey,            // [E*G][T]
    int* __restrict__ flags,           // zeroed by kernel 1; flags[g*16]
    const double* __restrict__ zpart,
    int nzpart,
    float* __restrict__ out,
    long long nout4, int out_size,
    int T, int G, int cap, long long GT)
{
    __shared__ Smem2 sm;
    const int b = blockIdx.x;
    const int tid = threadIdx.x;
    const int lane = tid & 63;
    const int wv = tid >> 6;

    if (b < NRANK) {
        // ---- ranksort slice: pair = e*G+g, 1/8 of its 2048 tokens ----
        const int pair = b >> 3;
        const int sub  = b & 7;
        const int e = pair / G;
        const int g = pair - e * G;
        const float* p = probsT + (long long)e * GT + (long long)g * T;
        for (int j = tid; j < 2048; j += 1024)
            sm.b.keys[j] = ((u64)__float_as_uint(p[j]) << 32) | (u32)(~(u32)j);
        __syncthreads();
        const int slot = tid & 255;
        const int q = tid >> 8;            // compare-range quarter 0..3
        const u64 kt = sm.b.keys[sub * 256 + slot];
        const ulonglong2* k2p = reinterpret_cast<const ulonglong2*>(sm.b.keys) + q * 256;
        int r = 0;
#pragma unroll 8
        for (int j = 0; j < 256; ++j) {
            const ulonglong2 v = k2p[j];
            r += (v.x > kt); r += (v.y > kt);
        }
        sm.b.part[tid] = r;
        __syncthreads();
        if (tid < 256) {
            const int rank = sm.b.part[tid] + sm.b.part[tid + 256] + sm.b.part[tid + 512] + sm.b.part[tid + 768];
            STORE_AGT(&skey[(long long)pair * T + rank], sm.b.keys[sub * 256 + tid]);
        }
        asm volatile("s_waitcnt vmcnt(0)" ::: "memory");   // per-wave: skey at LLC
        __syncthreads();
        if (tid == 0) atomicAdd(&flags[g * 16], 1);        // relaxed release (LLC channel)
        return;
    }

    // ---- assign block for group g: wait for its 64 producer blocks ----
    const int g = b - NRANK;
    if (tid == 0) {
        while (LOAD_AGT(&flags[g * 16]) < NRANK / 4)
            __builtin_amdgcn_s_sleep(2);
    }
    __syncthreads();

    u64 ka[NEXP], kb[NEXP];               // prefetch all experts' keys (LLC loads)
#pragma unroll
    for (int e = 0; e < NEXP; ++e) {
        const long long base = (long long)(e * G + g) * T;
        ka[e] = LOAD_AGT(&skey[base + tid]);
        kb[e] = LOAD_AGT(&skey[base + tid + 1024]);
    }
    sm.c.avail[tid] = 1;
    sm.c.avail[tid + 1024] = 1;

    float* dispatch = out;
    float* combine  = out + GT * (long long)NEXP * cap;
    const long long gbase = (long long)g * T;
    const u64 lmask = (lane == 0) ? 0ull : ((~0ull) >> (64 - lane));

    for (int e = 0; e < NEXP; ++e) {
        __syncthreads();                  // B_top: prev updates / init visible
        const u64 k0 = ka[e], k1 = kb[e];
        const u32 idx0 = ~(u32)k0, idx1 = ~(u32)k1;
        const float v0 = __uint_as_float((u32)(k0 >> 32));
        const float v1 = __uint_as_float((u32)(k1 >> 32));
        const int f0 = sm.c.avail[idx0];
        const int f1 = sm.c.avail[idx1];
        const u64 m0 = __ballot(f0);
        const u64 m1 = __ballot(f1);
        if (lane == 0) { sm.c.cnt[wv] = __popcll(m0); sm.c.cnt[16 + wv] = __popcll(m1); }
        __syncthreads();                  // B1
        int vi = (lane < 32) ? sm.c.cnt[lane] : 0;
#pragma unroll
        for (int o = 1; o < 32; o <<= 1) { const int t2 = __shfl_up(vi, o, 64); if (lane >= o) vi += t2; }
        const int off0 = wv ? __shfl(vi, wv - 1, 64) : 0;
        const int off1 = __shfl(vi, 15 + wv, 64);
        const int S    = __shfl(vi, 31, 64);
        const int pre0 = off0 + __popcll(m0 & lmask);
        const int pre1 = off1 + __popcll(m1 & lmask);
        const bool s0 = f0 && (pre0 < cap);
        const bool s1 = f1 && (pre1 < cap);
        if (s0) { const long long o_ = ((gbase + idx0) * NEXP + e) * (long long)cap + pre0; dispatch[o_] = 1.0f; combine[o_] = v0; }
        if (s1) { const long long o_ = ((gbase + idx1) * NEXP + e) * (long long)cap + pre1; dispatch[o_] = 1.0f; combine[o_] = v1; }
        if (S < cap) {
            // zero-gate fill: smallest-index unavailable tokens (combine stays 0)
            const int u0 = 1 - sm.c.avail[tid];
            const int u1 = 1 - sm.c.avail[tid + 1024];
            const u64 n0 = __ballot(u0);
            const u64 n1 = __ballot(u1);
            if (lane == 0) { sm.c.cnt2[wv] = __popcll(n0); sm.c.cnt2[16 + wv] = __popcll(n1); }
            __syncthreads();              // B2: cnt2 visible; orders u-reads before updates
            int vj = (lane < 32) ? sm.c.cnt2[lane] : 0;
#pragma unroll
            for (int o = 1; o < 32; o <<= 1) { const int t2 = __shfl_up(vj, o, 64); if (lane >= o) vj += t2; }
            const int qoff0 = wv ? __shfl(vj, wv - 1, 64) : 0;
            const int qoff1 = __shfl(vj, 15 + wv, 64);
            const int q0 = qoff0 + __popcll(n0 & lmask);
            const int q1 = qoff1 + __popcll(n1 & lmask);
            const int nfill = cap - S;
            if (u0 && q0 < nfill) { const long long o_ = ((gbase + tid) * NEXP + e) * (long long)cap + S + q0; dispatch[o_] = 1.0f; }
            if (u1 && q1 < nfill) { const long long o_ = ((gbase + tid + 1024) * NEXP + e) * (long long)cap + S + q1; dispatch[o_] = 1.0f; }
        }
        if (s0) sm.c.avail[idx0] = 0;     // after B1 (f-reads) / B2 (u-reads)
        if (s1) sm.c.avail[idx1] = 0;
    }

    // z_loss + tail scalars (group-0 assign block)
    if (g == 0) {
        __syncthreads();
        if (tid < 64) {
            double s = 0.0;
            for (int i = tid; i < nzpart; i += 64) s += zpart[i];
#pragma unroll
            for (int o = 32; o; o >>= 1) s += __shfl_xor(s, o, 64);
            if (tid == 0) {
                float* sc = out + 2 * GT * (long long)NEXP * cap;
                for (long long j = nout4 * 4; j < (long long)out_size - 3; ++j) out[j] = 0.f;
                sc[0] = 0.0f;
                sc[1] = (float)(s / (double)GT);
                sc[2] = 0.0f;
            }
        }
    }
}

extern "C" void kernel_launch(void* const* d_in, const int* in_sizes, int n_in,
                              void* d_out, int out_size, void* d_ws, size_t ws_size,
                              hipStream_t stream) {
    (void)n_in; (void)ws_size;
    const float* x    = (const float*)d_in[0];
    const float* w    = (const float*)d_in[1];
    const float* bias = (const float*)d_in[2];

    const int E = in_sizes[2];                        // 8
    const int D = in_sizes[1] / E;                    // 1024
    const long long GT = (long long)in_sizes[0] / D;  // 8192
    const int T = 2048;
    const int G = (int)(GT / T);                      // 4
    const int cap = (int)(((long long)out_size - 3) / (2 * GT * E));
    const int npb = (int)(GT / 8);                    // 1024 probs blocks
    const int nfb = 2048;                             // fill blocks

    int*    flags  = (int*)d_ws;                                   // [0,256)
    double* zpart  = (double*)((char*)d_ws + 4096);                // npb*8 B
    float*  probsT = (float*)((char*)d_ws + 16384);                // E*GT*4
    u64*    skey   = (u64*)((char*)d_ws + 16384 + (size_t)E * GT * sizeof(float));

    const long long nout4 = ((long long)out_size - 3) >> 2;

    probs_fill_kernel<<<npb + nfb, 512, 0, stream>>>(
        x, w, bias, probsT, zpart, flags, (float*)d_out, nout4, GT, npb, nfb);

    rank_assign_kernel<<<NRANK + G, 1024, 0, stream>>>(
        probsT, skey, flags, zpart, npb, (float*)d_out, nout4, out_size, T, G, cap, GT);
}